// Round 3
// baseline (1165.576 us; speedup 1.0000x reference)
//
#include <hip/hip_runtime.h>
#include <hip/hip_bf16.h>
#include <cstdint>

#define N_ROWS 8192
#define M_ROWS 8192
#define DDIM   256
#define EPSF   1e-12f
#define CAND_CAP (1 << 18)
#define THRESH_FRAC 0.08f

typedef unsigned short u16;
typedef unsigned long long u64;
typedef __attribute__((ext_vector_type(8))) short short8;
typedef __attribute__((ext_vector_type(4))) float floatx4;

// ---------------- prep x: x2, params {k,C,logk}, bf16 hi, d2-minmax init ----------------
__global__ __launch_bounds__(256) void prep_x(
    const float* __restrict__ x, const float* __restrict__ W, const float* __restrict__ b,
    u16* __restrict__ xhi, float* __restrict__ x2, float4* __restrict__ rowQ,
    unsigned* __restrict__ rowD2MinU, unsigned* __restrict__ rowD2MaxU)
{
    const int l = threadIdx.x & 63;
    const int w = threadIdx.x >> 6;
    const int row = blockIdx.x * 4 + w;

    const float4 xv = *(const float4*)(x + (size_t)row * DDIM + l * 4);
    const float4 wa = *(const float4*)(W + l * 8);
    const float4 wb = *(const float4*)(W + l * 8 + 4);

    float s2 = xv.x * xv.x + xv.y * xv.y + xv.z * xv.z + xv.w * xv.w;
    float s0 = xv.x * wa.x + xv.y * wa.z + xv.z * wb.x + xv.w * wb.z;
    float s1 = xv.x * wa.y + xv.y * wa.w + xv.z * wb.y + xv.w * wb.w;

    ushort4 hv;
    hv.x = __builtin_bit_cast(u16, __float2bfloat16(xv.x));
    hv.y = __builtin_bit_cast(u16, __float2bfloat16(xv.y));
    hv.z = __builtin_bit_cast(u16, __float2bfloat16(xv.z));
    hv.w = __builtin_bit_cast(u16, __float2bfloat16(xv.w));
    *(ushort4*)(xhi + (size_t)row * DDIM + l * 4) = hv;

    #pragma unroll
    for (int off = 32; off; off >>= 1) {
        s2 += __shfl_xor(s2, off);
        s0 += __shfl_xor(s0, off);
        s1 += __shfl_xor(s1, off);
    }
    if (l == 0) {
        float a0 = s0 + b[0];
        float a1 = s1 + b[1];
        float k = 1.0f / (1.0f + __expf(-a0));
        float t = 1.0f / (1.0f + __expf(-a1));
        k = fminf(fmaxf(k, EPSF), 1.0f - EPSF);
        t = fminf(fmaxf(t, EPSF), 1.0f - EPSF);
        x2[row] = s2;
        rowQ[row] = make_float4(k, t / (1.0f - t), logf(k), 0.0f);
        rowD2MinU[row] = 0x7F7FFFFFu;  // FLT_MAX bits (positive-float unsigned compare)
        rowD2MaxU[row] = 0u;
    }
}

// ---------------- prep x_n: xn2, bf16 hi ----------------
__global__ __launch_bounds__(256) void prep_xn(
    const float* __restrict__ xn, u16* __restrict__ xnhi, float* __restrict__ xn2)
{
    const int l = threadIdx.x & 63;
    const int w = threadIdx.x >> 6;
    const int row = blockIdx.x * 4 + w;

    const float4 xv = *(const float4*)(xn + (size_t)row * DDIM + l * 4);
    float s2 = xv.x * xv.x + xv.y * xv.y + xv.z * xv.z + xv.w * xv.w;

    ushort4 hv;
    hv.x = __builtin_bit_cast(u16, __float2bfloat16(xv.x));
    hv.y = __builtin_bit_cast(u16, __float2bfloat16(xv.y));
    hv.z = __builtin_bit_cast(u16, __float2bfloat16(xv.z));
    hv.w = __builtin_bit_cast(u16, __float2bfloat16(xv.w));
    *(ushort4*)(xnhi + (size_t)row * DDIM + l * 4) = hv;

    #pragma unroll
    for (int off = 32; off; off >>= 1) s2 += __shfl_xor(s2, off);
    if (l == 0) xn2[row] = s2;
}

// ---------------- shared GEMM core: 128x128 tile, 1-pass bf16, acc = x·xn^T ----------------
__device__ __forceinline__ void gemm_core(
    const u16* __restrict__ xhi, const u16* __restrict__ xnhi,
    u16* lds, int bRow, int bCol, int l, int w, int wm, int wn,
    floatx4 acc[4][4])
{
    const int lrow = l & 15;
    const int lk8  = (l >> 4) * 8;
    #pragma unroll
    for (int mi = 0; mi < 4; ++mi)
        #pragma unroll
        for (int ni = 0; ni < 4; ++ni)
            acc[mi][ni] = (floatx4){0.f, 0.f, 0.f, 0.f};

    for (int kk = 0; kk < DDIM / 32; ++kk) {
        const int ks = kk * 32;
        #pragma unroll
        for (int p = 0; p < 4; ++p) {
            const int id    = w * 4 + p;   // 0..15
            const int panel = id >> 3;     // 0: x-hi, 1: xn-hi
            const int tile  = id & 7;      // 16 rows each
            const int grow  = (panel == 0 ? bRow : bCol) * 128 + tile * 16 + lrow;
            const u16* src  = (panel == 0 ? xhi : xnhi) + (size_t)grow * DDIM + ks + lk8;
            u16* dst = &lds[panel * 4096 + tile * 512];  // wave-uniform base, lane*16B
            __builtin_amdgcn_global_load_lds(
                (const __attribute__((address_space(1))) void*)src,
                (__attribute__((address_space(3))) void*)dst,
                16, 0, 0);
        }
        __syncthreads();

        short8 ah[4], bh[4];
        #pragma unroll
        for (int i = 0; i < 4; ++i) {
            ah[i] = *(const short8*)&lds[0    + (wm * 4 + i) * 512 + l * 8];
            bh[i] = *(const short8*)&lds[4096 + (wn * 4 + i) * 512 + l * 8];
        }
        #pragma unroll
        for (int mi = 0; mi < 4; ++mi)
            #pragma unroll
            for (int ni = 0; ni < 4; ++ni)
                acc[mi][ni] = __builtin_amdgcn_mfma_f32_16x16x32_bf16(ah[mi], bh[ni], acc[mi][ni], 0, 0, 0);
        __syncthreads();
    }
}

// ---------------- GEMM pass A: per-row d2 min/max only (no writes) ----------------
__global__ __launch_bounds__(256) void gemm_minmax(
    const u16* __restrict__ xhi, const u16* __restrict__ xnhi,
    const float* __restrict__ x2, const float* __restrict__ xn2,
    unsigned* __restrict__ rowD2MinU, unsigned* __restrict__ rowD2MaxU)
{
    __shared__ u16 lds[8192];
    const int l  = threadIdx.x & 63;
    const int w  = threadIdx.x >> 6;
    const int wm = w >> 1;
    const int wn = w & 1;
    const int bRow = blockIdx.y;
    const int bCol = blockIdx.x;

    floatx4 acc[4][4];
    gemm_core(xhi, xnhi, lds, bRow, bCol, l, w, wm, wn, acc);

    const int q  = l >> 4;
    const int cn = l & 15;
    #pragma unroll
    for (int mi = 0; mi < 4; ++mi) {
        #pragma unroll
        for (int r = 0; r < 4; ++r) {
            const int i = bRow * 128 + wm * 64 + mi * 16 + q * 4 + r;
            const float x2i = x2[i];
            float dmn = 3.0e38f, dmx = 0.0f;
            #pragma unroll
            for (int ni = 0; ni < 4; ++ni) {
                const int j = bCol * 128 + wn * 64 + ni * 16 + cn;
                const float d2 = fmaxf(x2i + xn2[j] - 2.0f * acc[mi][ni][r], 0.0f);
                dmn = fminf(dmn, d2);
                dmx = fmaxf(dmx, d2);
            }
            #pragma unroll
            for (int m = 1; m < 16; m <<= 1) {
                dmn = fminf(dmn, __shfl_xor(dmn, m));
                dmx = fmaxf(dmx, __shfl_xor(dmx, m));
            }
            if (cn == 0) {
                atomicMin(&rowD2MinU[i], __float_as_uint(dmn));
                atomicMax(&rowD2MaxU[i], __float_as_uint(dmx));
            }
        }
    }
}

// ---------------- rowfin: per-row {smin, inv, thresh, smax}; reset counter & exact-min ----------------
__global__ __launch_bounds__(256) void rowfin(
    const unsigned* __restrict__ rowD2MinU, const unsigned* __restrict__ rowD2MaxU,
    float4* __restrict__ rowP, u64* __restrict__ rowMinBits, int* __restrict__ cntG)
{
    const int i = blockIdx.x * 256 + threadIdx.x;
    const float smax = -sqrtf(__uint_as_float(rowD2MinU[i]));
    const float smin = -sqrtf(__uint_as_float(rowD2MaxU[i]));
    const float range = smax - smin;
    rowP[i] = make_float4(smin, 1.0f / range, smin + THRESH_FRAC * range, smax);
    rowMinBits[i] = 0ull;  // +0.0 bits: any negative double wins unsigned atomicMax
    if (i == 0) *cntG = 0;
}

// ---------------- GEMM pass B: fused transform + candidate recording ----------------
__global__ __launch_bounds__(256) void gemm_out(
    const u16* __restrict__ xhi, const u16* __restrict__ xnhi,
    const float* __restrict__ x2, const float* __restrict__ xn2,
    const float4* __restrict__ rowP, const float4* __restrict__ rowQ,
    float* __restrict__ out, unsigned* __restrict__ cand, int* __restrict__ cntG)
{
    __shared__ u16 lds[8192];
    const int l  = threadIdx.x & 63;
    const int w  = threadIdx.x >> 6;
    const int wm = w >> 1;
    const int wn = w & 1;
    const int bRow = blockIdx.y;
    const int bCol = blockIdx.x;

    floatx4 acc[4][4];
    gemm_core(xhi, xnhi, lds, bRow, bCol, l, w, wm, wn, acc);

    const int q  = l >> 4;
    const int cn = l & 15;
    #pragma unroll
    for (int mi = 0; mi < 4; ++mi) {
        #pragma unroll
        for (int r = 0; r < 4; ++r) {
            const int i = bRow * 128 + wm * 64 + mi * 16 + q * 4 + r;
            const float x2i  = x2[i];
            const float4 P = rowP[i];  // smin, inv, thresh, smax
            const float4 Q = rowQ[i];  // k, C, logk
            #pragma unroll
            for (int ni = 0; ni < 4; ++ni) {
                const int j = bCol * 128 + wn * 64 + ni * 16 + cn;
                const float d2 = fmaxf(x2i + xn2[j] - 2.0f * acc[mi][ni][r], 0.0f);
                const float s = -sqrtf(d2);
                if (s <= P.z) {
                    int pos = atomicAdd(cntG, 1);
                    if (pos < CAND_CAP) cand[pos] = ((unsigned)i << 13) | (unsigned)j;
                }
                float sim = fmaxf((s - P.x) * P.y, EPSF);
                float rv = sim;
                if (sim <= Q.x) rv += Q.y * (Q.x - sim) * (__logf(sim) - Q.z);
                __builtin_nontemporal_store(rv, &out[(size_t)i * M_ROWS + j]);
            }
        }
    }
}

// ---------------- refine: fp64 exact s per candidate + exact row min ----------------
__global__ __launch_bounds__(256) void refine(
    const float* __restrict__ x, const float* __restrict__ xn,
    const unsigned* __restrict__ cand, const int* __restrict__ cntG,
    double* __restrict__ cexact, u64* __restrict__ rowMinBits)
{
    const int l = threadIdx.x & 63;
    const int w = threadIdx.x >> 6;
    const int gw = blockIdx.x * 4 + w;
    const int nwaves = gridDim.x * 4;
    const int nc = min(*cntG, CAND_CAP);

    for (int c = gw; c < nc; c += nwaves) {
        const unsigned rc = cand[c];
        const int row = rc >> 13;
        const int col = rc & 8191;
        const float4 xa = *(const float4*)(x  + (size_t)row * DDIM + l * 4);
        const float4 na = *(const float4*)(xn + (size_t)col * DDIM + l * 4);
        const double x0 = xa.x, x1 = xa.y, x2v = xa.z, x3 = xa.w;
        const double n0 = na.x, n1 = na.y, n2v = na.z, n3 = na.w;
        double xx  = x0 * x0 + x1 * x1 + x2v * x2v + x3 * x3;
        double nn  = n0 * n0 + n1 * n1 + n2v * n2v + n3 * n3;
        double dot = x0 * n0 + x1 * n1 + x2v * n2v + x3 * n3;
        #pragma unroll
        for (int m = 1; m < 64; m <<= 1) {
            xx  += __shfl_xor(xx, m);
            nn  += __shfl_xor(nn, m);
            dot += __shfl_xor(dot, m);
        }
        if (l == 0) {
            double d2 = xx + nn - 2.0 * dot;
            d2 = d2 > 0.0 ? d2 : 0.0;
            const double se = -sqrt(d2);
            cexact[c] = se;
            atomicMax(&rowMinBits[row], (u64)__double_as_longlong(se));
        }
    }
}

// ---------------- patch: overwrite candidate outputs with fp64-accurate path ----------------
__global__ __launch_bounds__(256) void patch(
    const unsigned* __restrict__ cand, const int* __restrict__ cntG,
    const double* __restrict__ cexact, const u64* __restrict__ rowMinBits,
    const float4* __restrict__ rowP, const float4* __restrict__ rowQ,
    float* __restrict__ out)
{
    const int nc = min(*cntG, CAND_CAP);
    for (int c = blockIdx.x * 256 + threadIdx.x; c < nc; c += gridDim.x * 256) {
        const unsigned rc = cand[c];
        const int row = rc >> 13;
        const int col = rc & 8191;
        const double se = cexact[c];
        const double sminD = __longlong_as_double((long long)rowMinBits[row]);
        const double invD = 1.0 / ((double)rowP[row].w - sminD);
        double simd = (se - sminD) * invD;
        simd = simd > (double)EPSF ? simd : (double)EPSF;
        const float sim = (float)simd;
        const float4 Q = rowQ[row];
        float rv = sim;
        if (sim <= Q.x) rv += Q.y * (Q.x - sim) * (logf(sim) - Q.z);
        out[(size_t)row * M_ROWS + col] = rv;
    }
}

// ---------------- launch ----------------
extern "C" void kernel_launch(void* const* d_in, const int* in_sizes, int n_in,
                              void* d_out, int out_size, void* d_ws, size_t ws_size,
                              hipStream_t stream)
{
    const float* x  = (const float*)d_in[0];
    const float* xn = (const float*)d_in[1];
    const float* W  = (const float*)d_in[2];
    const float* b  = (const float*)d_in[3];
    float* out = (float*)d_out;

    uint8_t* ws = (uint8_t*)d_ws;
    u16* xhi   = (u16*)(ws);                       // 4 MB
    u16* xnhi  = (u16*)(ws + (4u << 20));          // 4 MB
    float* x2  = (float*)(ws + (8u << 20));        // 32 KB
    float* xn2 = x2 + N_ROWS;                      // 32 KB
    float4* rowQ = (float4*)(xn2 + M_ROWS);        // 128 KB
    float4* rowP = rowQ + N_ROWS;                  // 128 KB
    unsigned* rowD2MinU = (unsigned*)(rowP + N_ROWS);   // 32 KB
    unsigned* rowD2MaxU = rowD2MinU + N_ROWS;           // 32 KB
    u64* rowMinBits = (u64*)(rowD2MaxU + N_ROWS);       // 64 KB
    int* cntG = (int*)(rowMinBits + N_ROWS);            // pad to 16B
    unsigned* cand = (unsigned*)((uint8_t*)cntG + 16);  // 1 MB
    double* cexact = (double*)((uint8_t*)cand + (size_t)CAND_CAP * 4);  // 2 MB

    prep_x<<<N_ROWS / 4, 256, 0, stream>>>(x, W, b, xhi, x2, rowQ, rowD2MinU, rowD2MaxU);
    prep_xn<<<M_ROWS / 4, 256, 0, stream>>>(xn, xnhi, xn2);
    gemm_minmax<<<dim3(M_ROWS / 128, N_ROWS / 128), 256, 0, stream>>>(
        xhi, xnhi, x2, xn2, rowD2MinU, rowD2MaxU);
    rowfin<<<N_ROWS / 256, 256, 0, stream>>>(rowD2MinU, rowD2MaxU, rowP, rowMinBits, cntG);
    gemm_out<<<dim3(M_ROWS / 128, N_ROWS / 128), 256, 0, stream>>>(
        xhi, xnhi, x2, xn2, rowP, rowQ, out, cand, cntG);
    refine<<<512, 256, 0, stream>>>(x, xn, cand, cntG, cexact, rowMinBits);
    patch<<<256, 256, 0, stream>>>(cand, cntG, cexact, rowMinBits, rowP, rowQ, out);
}